// Round 2
// baseline (188.058 us; speedup 1.0000x reference)
//
#include <hip/hip_runtime.h>

#define LN_EPS 1e-5f
#define D 768
#define D4 192          // D/4
#define TWO_D 1536

// One wave per 2 rows per grid-stride iteration.
// Key algebraic refactor: logits l_k = rstd*(A_k - mean*C_k) + E_k + b_k where
//   A_k = sum_i h_i * gamma_i * w_k_i   (per-row, reduced)
//   C_k = sum_i gamma_i * w_k_i         (row-independent, computed once/wave)
//   E_k = sum_i beta_i  * w_k_i         (row-independent)
// -> single shuffle-reduction round per row (4 values, ILP-4 chains) and zero
//    per-row parameter loads (gamma*w_k cached in 48 VGPRs per lane).
__global__ __launch_bounds__(256, 4) void fused_gate_kernel(
    const float* __restrict__ seq, const float* __restrict__ msa,
    const float* __restrict__ gamma, const float* __restrict__ beta,
    const float* __restrict__ gate_w, const float* __restrict__ gate_b,
    float* __restrict__ out, int nrows, int nwaves)
{
    const int lane = threadIdx.x & 63;
    const int wid  = (int)((blockIdx.x * blockDim.x + threadIdx.x) >> 6);

    // ---- per-wave precompute ----
    const float4* g4  = (const float4*)gamma;
    const float4* b4  = (const float4*)beta;
    const float4* w04 = (const float4*)gate_w;
    const float4* w14 = (const float4*)(gate_w + TWO_D);

    float4 P0[6], P1[6];   // gamma*w0 / gamma*w1; [0..2]=seq half, [3..5]=msa half
    float C0 = 0.f, C1 = 0.f, E0 = 0.f, E1 = 0.f;
    #pragma unroll
    for (int j = 0; j < 6; ++j) {
        const int idx = (j < 3) ? (j * 64 + lane) : (D4 + (j - 3) * 64 + lane);
        float4 g = g4[idx], bb = b4[idx], w0 = w04[idx], w1 = w14[idx];
        P0[j].x = g.x * w0.x; P0[j].y = g.y * w0.y; P0[j].z = g.z * w0.z; P0[j].w = g.w * w0.w;
        P1[j].x = g.x * w1.x; P1[j].y = g.y * w1.y; P1[j].z = g.z * w1.z; P1[j].w = g.w * w1.w;
        C0 += P0[j].x + P0[j].y + P0[j].z + P0[j].w;
        C1 += P1[j].x + P1[j].y + P1[j].z + P1[j].w;
        E0 += bb.x * w0.x + bb.y * w0.y + bb.z * w0.z + bb.w * w0.w;
        E1 += bb.x * w1.x + bb.y * w1.y + bb.z * w1.z + bb.w * w1.w;
    }
    #pragma unroll
    for (int off = 32; off > 0; off >>= 1) {
        C0 += __shfl_xor(C0, off, 64);
        C1 += __shfl_xor(C1, off, 64);
        E0 += __shfl_xor(E0, off, 64);
        E1 += __shfl_xor(E1, off, 64);
    }
    const float gb0 = gate_b[0], gb1 = gate_b[1];
    const float inv_n = 1.f / (float)TWO_D;

    // ---- grid-stride over row pairs ----
    for (int base = wid * 2; base < nrows; base += nwaves * 2) {
        const int r0 = base;
        const bool has1 = (base + 1) < nrows;
        const int r1 = has1 ? (base + 1) : base;

        const float4* s0p = (const float4*)(seq + (size_t)r0 * D);
        const float4* m0p = (const float4*)(msa + (size_t)r0 * D);
        const float4* s1p = (const float4*)(seq + (size_t)r1 * D);
        const float4* m1p = (const float4*)(msa + (size_t)r1 * D);

        float4 s0[3], m0[3], s1[3], m1[3];
        #pragma unroll
        for (int j = 0; j < 3; ++j) {
            s0[j] = s0p[j * 64 + lane];
            m0[j] = m0p[j * 64 + lane];
            s1[j] = s1p[j * 64 + lane];
            m1[j] = m1p[j * 64 + lane];
        }

        // ---- fused single-pass accumulation (both rows) ----
        float su0 = 0.f, sq0 = 0.f, a00 = 0.f, a01 = 0.f;
        float su1 = 0.f, sq1 = 0.f, a10 = 0.f, a11 = 0.f;
        #pragma unroll
        for (int j = 0; j < 3; ++j) {
            // row 0, seq half (params P*[j]); msa half (params P*[j+3])
            {
                float4 h = s0[j];
                su0 += h.x + h.y + h.z + h.w;
                sq0 += h.x*h.x + h.y*h.y + h.z*h.z + h.w*h.w;
                a00 += h.x*P0[j].x + h.y*P0[j].y + h.z*P0[j].z + h.w*P0[j].w;
                a01 += h.x*P1[j].x + h.y*P1[j].y + h.z*P1[j].z + h.w*P1[j].w;
            }
            {
                float4 h = m0[j];
                su0 += h.x + h.y + h.z + h.w;
                sq0 += h.x*h.x + h.y*h.y + h.z*h.z + h.w*h.w;
                a00 += h.x*P0[j+3].x + h.y*P0[j+3].y + h.z*P0[j+3].z + h.w*P0[j+3].w;
                a01 += h.x*P1[j+3].x + h.y*P1[j+3].y + h.z*P1[j+3].z + h.w*P1[j+3].w;
            }
            {
                float4 h = s1[j];
                su1 += h.x + h.y + h.z + h.w;
                sq1 += h.x*h.x + h.y*h.y + h.z*h.z + h.w*h.w;
                a10 += h.x*P0[j].x + h.y*P0[j].y + h.z*P0[j].z + h.w*P0[j].w;
                a11 += h.x*P1[j].x + h.y*P1[j].y + h.z*P1[j].z + h.w*P1[j].w;
            }
            {
                float4 h = m1[j];
                su1 += h.x + h.y + h.z + h.w;
                sq1 += h.x*h.x + h.y*h.y + h.z*h.z + h.w*h.w;
                a10 += h.x*P0[j+3].x + h.y*P0[j+3].y + h.z*P0[j+3].z + h.w*P0[j+3].w;
                a11 += h.x*P1[j+3].x + h.y*P1[j+3].y + h.z*P1[j+3].z + h.w*P1[j+3].w;
            }
        }

        // ---- one reduction round, 8 independent chains ----
        #pragma unroll
        for (int off = 32; off > 0; off >>= 1) {
            su0 += __shfl_xor(su0, off, 64);
            sq0 += __shfl_xor(sq0, off, 64);
            a00 += __shfl_xor(a00, off, 64);
            a01 += __shfl_xor(a01, off, 64);
            su1 += __shfl_xor(su1, off, 64);
            sq1 += __shfl_xor(sq1, off, 64);
            a10 += __shfl_xor(a10, off, 64);
            a11 += __shfl_xor(a11, off, 64);
        }

        // ---- epilogue row 0 ----
        {
            const float mean = su0 * inv_n;
            const float var  = fmaxf(sq0 * inv_n - mean * mean, 0.f);
            const float rstd = rsqrtf(var + LN_EPS);
            const float l0 = rstd * (a00 - mean * C0) + E0 + gb0;
            const float l1 = rstd * (a01 - mean * C1) + E1 + gb1;
            const float mx = fmaxf(l0, l1);
            const float e0 = __expf(l0 - mx), e1 = __expf(l1 - mx);
            const float inv = 1.f / (e0 + e1);
            const float w0s = e0 * inv, w1s = e1 * inv;
            float4* o4 = (float4*)(out + (size_t)r0 * D);
            #pragma unroll
            for (int j = 0; j < 3; ++j) {
                float4 o;
                o.x = w0s * s0[j].x + w1s * m0[j].x;
                o.y = w0s * s0[j].y + w1s * m0[j].y;
                o.z = w0s * s0[j].z + w1s * m0[j].z;
                o.w = w0s * s0[j].w + w1s * m0[j].w;
                o4[j * 64 + lane] = o;
            }
        }
        // ---- epilogue row 1 ----
        if (has1) {
            const float mean = su1 * inv_n;
            const float var  = fmaxf(sq1 * inv_n - mean * mean, 0.f);
            const float rstd = rsqrtf(var + LN_EPS);
            const float l0 = rstd * (a10 - mean * C0) + E0 + gb0;
            const float l1 = rstd * (a11 - mean * C1) + E1 + gb1;
            const float mx = fmaxf(l0, l1);
            const float e0 = __expf(l0 - mx), e1 = __expf(l1 - mx);
            const float inv = 1.f / (e0 + e1);
            const float w0s = e0 * inv, w1s = e1 * inv;
            float4* o4 = (float4*)(out + (size_t)r1 * D);
            #pragma unroll
            for (int j = 0; j < 3; ++j) {
                float4 o;
                o.x = w0s * s1[j].x + w1s * m1[j].x;
                o.y = w0s * s1[j].y + w1s * m1[j].y;
                o.z = w0s * s1[j].z + w1s * m1[j].z;
                o.w = w0s * s1[j].w + w1s * m1[j].w;
                o4[j * 64 + lane] = o;
            }
        }
    }
}

extern "C" void kernel_launch(void* const* d_in, const int* in_sizes, int n_in,
                              void* d_out, int out_size, void* d_ws, size_t ws_size,
                              hipStream_t stream) {
    const float* seq    = (const float*)d_in[0];
    const float* msa    = (const float*)d_in[1];
    const float* gamma  = (const float*)d_in[2];
    const float* beta   = (const float*)d_in[3];
    const float* gate_w = (const float*)d_in[4];
    const float* gate_b = (const float*)d_in[5];
    float* out = (float*)d_out;

    const int nrows = in_sizes[0] / D;      // 16384
    const int blocks = 1024;                // 4 blocks/CU resident at launch_bounds(256,4)
    const int nwaves = blocks * 4;          // wave64 per 256-thread block
    fused_gate_kernel<<<blocks, 256, 0, stream>>>(
        seq, msa, gamma, beta, gate_w, gate_b, out, nrows, nwaves);
}

// Round 3
// 146.359 us; speedup vs baseline: 1.2849x; 1.2849x over previous
//
#include <hip/hip_runtime.h>

#define LN_EPS 1e-5f
#define D 768
#define D4 192          // D/4
#define TWO_D 1536

// ws layout (floats): P0[1536] = gamma*w0, P1[1536] = gamma*w1,
//                     consts[4] = {C0, C1, E0+gb0, E1+gb1}
// where C_k = sum gamma*w_k, E_k = sum beta*w_k.
// Logits: l_k = rstd*(A_k - mean*C_k) + E_k + gb_k, A_k = sum h*gamma*w_k.

__global__ __launch_bounds__(64) void setup_kernel(
    const float* __restrict__ gamma, const float* __restrict__ beta,
    const float* __restrict__ gate_w, const float* __restrict__ gate_b,
    float* __restrict__ ws)
{
    const int lane = threadIdx.x;           // single wave
    const float4* g4  = (const float4*)gamma;
    const float4* b4  = (const float4*)beta;
    const float4* w04 = (const float4*)gate_w;
    const float4* w14 = (const float4*)(gate_w + TWO_D);
    float4* P04 = (float4*)ws;
    float4* P14 = (float4*)(ws + TWO_D);

    float C0 = 0.f, C1 = 0.f, E0 = 0.f, E1 = 0.f;
    #pragma unroll
    for (int j = 0; j < 6; ++j) {
        const int idx = j * 64 + lane;
        float4 g = g4[idx], bb = b4[idx], w0 = w04[idx], w1 = w14[idx];
        float4 p0, p1;
        p0.x = g.x * w0.x; p0.y = g.y * w0.y; p0.z = g.z * w0.z; p0.w = g.w * w0.w;
        p1.x = g.x * w1.x; p1.y = g.y * w1.y; p1.z = g.z * w1.z; p1.w = g.w * w1.w;
        P04[idx] = p0;
        P14[idx] = p1;
        C0 += p0.x + p0.y + p0.z + p0.w;
        C1 += p1.x + p1.y + p1.z + p1.w;
        E0 += bb.x * w0.x + bb.y * w0.y + bb.z * w0.z + bb.w * w0.w;
        E1 += bb.x * w1.x + bb.y * w1.y + bb.z * w1.z + bb.w * w1.w;
    }
    #pragma unroll
    for (int off = 32; off > 0; off >>= 1) {
        C0 += __shfl_xor(C0, off, 64);
        C1 += __shfl_xor(C1, off, 64);
        E0 += __shfl_xor(E0, off, 64);
        E1 += __shfl_xor(E1, off, 64);
    }
    if (lane == 0) {
        float* c = ws + 2 * TWO_D;
        c[0] = C0;
        c[1] = C1;
        c[2] = E0 + gate_b[0];
        c[3] = E1 + gate_b[1];
    }
}

// One wave per row. Single load phase (all independent), single fused pass,
// single 4-chain butterfly reduction, epilogue, store.
__global__ __launch_bounds__(256) void fused_gate_kernel(
    const float* __restrict__ seq, const float* __restrict__ msa,
    const float* __restrict__ ws, float* __restrict__ out, int nrows)
{
    const int wave = threadIdx.x >> 6;
    const int lane = threadIdx.x & 63;
    const int row = blockIdx.x * 4 + wave;
    if (row >= nrows) return;

    const float4* s4 = (const float4*)(seq + (size_t)row * D);
    const float4* m4 = (const float4*)(msa + (size_t)row * D);
    const float4* P04 = (const float4*)ws;
    const float4* P14 = (const float4*)(ws + TWO_D);

    // data loads first (HBM, longest latency)
    float4 s[3], m[3];
    #pragma unroll
    for (int j = 0; j < 3; ++j) {
        s[j] = s4[j * 64 + lane];
        m[j] = m4[j * 64 + lane];
    }
    // constants (L2-broadcast)
    const float4 cst = *(const float4*)(ws + 2 * TWO_D);

    // ---- single fused pass: su, sq, a0, a1 ----
    float su = 0.f, sq = 0.f, a0 = 0.f, a1 = 0.f;
    #pragma unroll
    for (int j = 0; j < 6; ++j) {
        const int idx = (j < 3) ? (j * 64 + lane) : (D4 + (j - 3) * 64 + lane);
        const float4 p0 = P04[idx];
        const float4 p1 = P14[idx];
        const float4 h = (j < 3) ? s[j] : m[j - 3];
        su += h.x + h.y + h.z + h.w;
        sq += h.x * h.x + h.y * h.y + h.z * h.z + h.w * h.w;
        a0 += h.x * p0.x + h.y * p0.y + h.z * p0.z + h.w * p0.w;
        a1 += h.x * p1.x + h.y * p1.y + h.z * p1.z + h.w * p1.w;
    }
    #pragma unroll
    for (int off = 32; off > 0; off >>= 1) {
        su += __shfl_xor(su, off, 64);
        sq += __shfl_xor(sq, off, 64);
        a0 += __shfl_xor(a0, off, 64);
        a1 += __shfl_xor(a1, off, 64);
    }

    // ---- epilogue ----
    const float inv_n = 1.f / (float)TWO_D;
    const float mean = su * inv_n;
    const float var  = fmaxf(sq * inv_n - mean * mean, 0.f);
    const float rstd = rsqrtf(var + LN_EPS);
    const float l0 = rstd * (a0 - mean * cst.x) + cst.z;
    const float l1 = rstd * (a1 - mean * cst.y) + cst.w;
    const float mx = fmaxf(l0, l1);
    const float e0 = __expf(l0 - mx), e1 = __expf(l1 - mx);
    const float inv = 1.f / (e0 + e1);
    const float w0s = e0 * inv, w1s = e1 * inv;

    float4* o4 = (float4*)(out + (size_t)row * D);
    #pragma unroll
    for (int j = 0; j < 3; ++j) {
        float4 o;
        o.x = w0s * s[j].x + w1s * m[j].x;
        o.y = w0s * s[j].y + w1s * m[j].y;
        o.z = w0s * s[j].z + w1s * m[j].z;
        o.w = w0s * s[j].w + w1s * m[j].w;
        o4[j * 64 + lane] = o;
    }
}

extern "C" void kernel_launch(void* const* d_in, const int* in_sizes, int n_in,
                              void* d_out, int out_size, void* d_ws, size_t ws_size,
                              hipStream_t stream) {
    const float* seq    = (const float*)d_in[0];
    const float* msa    = (const float*)d_in[1];
    const float* gamma  = (const float*)d_in[2];
    const float* beta   = (const float*)d_in[3];
    const float* gate_w = (const float*)d_in[4];
    const float* gate_b = (const float*)d_in[5];
    float* out = (float*)d_out;
    float* ws  = (float*)d_ws;

    const int nrows = in_sizes[0] / D;      // 16384
    setup_kernel<<<1, 64, 0, stream>>>(gamma, beta, gate_w, gate_b, ws);
    fused_gate_kernel<<<(nrows + 3) / 4, 256, 0, stream>>>(seq, msa, ws, out, nrows);
}

// Round 4
// 146.335 us; speedup vs baseline: 1.2851x; 1.0002x over previous
//
#include <hip/hip_runtime.h>

#define LN_EPS 1e-5f
#define D 768
#define D4 192          // D/4
#define TWO_D 1536

typedef float f4 __attribute__((ext_vector_type(4)));

// ws layout (floats): P0[1536] = gamma*w0, P1[1536] = gamma*w1,
//                     consts[4] = {C0, C1, E0+gb0, E1+gb1}
// Logits: l_k = rstd*(A_k - mean*C_k) + E_k + gb_k, A_k = sum h*gamma*w_k.

__global__ __launch_bounds__(64) void setup_kernel(
    const float* __restrict__ gamma, const float* __restrict__ beta,
    const float* __restrict__ gate_w, const float* __restrict__ gate_b,
    float* __restrict__ ws)
{
    const int lane = threadIdx.x;           // single wave
    const f4* g4  = (const f4*)gamma;
    const f4* b4  = (const f4*)beta;
    const f4* w04 = (const f4*)gate_w;
    const f4* w14 = (const f4*)(gate_w + TWO_D);
    f4* P04 = (f4*)ws;
    f4* P14 = (f4*)(ws + TWO_D);

    float C0 = 0.f, C1 = 0.f, E0 = 0.f, E1 = 0.f;
    #pragma unroll
    for (int j = 0; j < 6; ++j) {
        const int idx = j * 64 + lane;
        f4 g = g4[idx], bb = b4[idx], w0 = w04[idx], w1 = w14[idx];
        f4 p0 = g * w0;
        f4 p1 = g * w1;
        P04[idx] = p0;
        P14[idx] = p1;
        C0 += p0.x + p0.y + p0.z + p0.w;
        C1 += p1.x + p1.y + p1.z + p1.w;
        E0 += bb.x * w0.x + bb.y * w0.y + bb.z * w0.z + bb.w * w0.w;
        E1 += bb.x * w1.x + bb.y * w1.y + bb.z * w1.z + bb.w * w1.w;
    }
    #pragma unroll
    for (int off = 32; off > 0; off >>= 1) {
        C0 += __shfl_xor(C0, off, 64);
        C1 += __shfl_xor(C1, off, 64);
        E0 += __shfl_xor(E0, off, 64);
        E1 += __shfl_xor(E1, off, 64);
    }
    if (lane == 0) {
        float* c = ws + 2 * TWO_D;
        c[0] = C0;
        c[1] = C1;
        c[2] = E0 + gate_b[0];
        c[3] = E1 + gate_b[1];
    }
}

// Two rows per wave. All 12 HBM loads issued up front (nontemporal — every
// element touched exactly once kernel-wide), P loads shared between rows,
// one 8-chain butterfly, two epilogues with nontemporal stores.
__global__ __launch_bounds__(256, 2) void fused_gate_kernel(
    const float* __restrict__ seq, const float* __restrict__ msa,
    const float* __restrict__ ws, float* __restrict__ out, int nrows)
{
    const int wave = threadIdx.x >> 6;
    const int lane = threadIdx.x & 63;
    const int r0 = (blockIdx.x * 4 + wave) * 2;
    if (r0 >= nrows) return;
    const bool has1 = (r0 + 1) < nrows;
    const int r1 = has1 ? (r0 + 1) : r0;

    const f4* s0p = (const f4*)(seq + (size_t)r0 * D);
    const f4* m0p = (const f4*)(msa + (size_t)r0 * D);
    const f4* s1p = (const f4*)(seq + (size_t)r1 * D);
    const f4* m1p = (const f4*)(msa + (size_t)r1 * D);
    const f4* P04 = (const f4*)ws;
    const f4* P14 = (const f4*)(ws + TWO_D);

    // ---- issue ALL data loads before any arithmetic (max MLP) ----
    f4 s0[3], m0[3], s1[3], m1[3];
    #pragma unroll
    for (int j = 0; j < 3; ++j) s0[j] = __builtin_nontemporal_load(&s0p[j * 64 + lane]);
    #pragma unroll
    for (int j = 0; j < 3; ++j) m0[j] = __builtin_nontemporal_load(&m0p[j * 64 + lane]);
    #pragma unroll
    for (int j = 0; j < 3; ++j) s1[j] = __builtin_nontemporal_load(&s1p[j * 64 + lane]);
    #pragma unroll
    for (int j = 0; j < 3; ++j) m1[j] = __builtin_nontemporal_load(&m1p[j * 64 + lane]);

    const f4 cst = *(const f4*)(ws + 2 * TWO_D);

    // ---- fused single pass, both rows share the P loads ----
    float su0 = 0.f, sq0 = 0.f, a00 = 0.f, a01 = 0.f;
    float su1 = 0.f, sq1 = 0.f, a10 = 0.f, a11 = 0.f;
    #pragma unroll
    for (int j = 0; j < 6; ++j) {
        const int idx = (j < 3) ? (j * 64 + lane) : (D4 + (j - 3) * 64 + lane);
        const f4 p0 = P04[idx];
        const f4 p1 = P14[idx];
        const f4 h0 = (j < 3) ? s0[j] : m0[j - 3];
        const f4 h1 = (j < 3) ? s1[j] : m1[j - 3];
        su0 += h0.x + h0.y + h0.z + h0.w;
        sq0 += h0.x * h0.x + h0.y * h0.y + h0.z * h0.z + h0.w * h0.w;
        a00 += h0.x * p0.x + h0.y * p0.y + h0.z * p0.z + h0.w * p0.w;
        a01 += h0.x * p1.x + h0.y * p1.y + h0.z * p1.z + h0.w * p1.w;
        su1 += h1.x + h1.y + h1.z + h1.w;
        sq1 += h1.x * h1.x + h1.y * h1.y + h1.z * h1.z + h1.w * h1.w;
        a10 += h1.x * p0.x + h1.y * p0.y + h1.z * p0.z + h1.w * p0.w;
        a11 += h1.x * p1.x + h1.y * p1.y + h1.z * p1.z + h1.w * p1.w;
    }

    // ---- one butterfly round, 8 independent chains ----
    #pragma unroll
    for (int off = 32; off > 0; off >>= 1) {
        su0 += __shfl_xor(su0, off, 64);
        sq0 += __shfl_xor(sq0, off, 64);
        a00 += __shfl_xor(a00, off, 64);
        a01 += __shfl_xor(a01, off, 64);
        su1 += __shfl_xor(su1, off, 64);
        sq1 += __shfl_xor(sq1, off, 64);
        a10 += __shfl_xor(a10, off, 64);
        a11 += __shfl_xor(a11, off, 64);
    }

    const float inv_n = 1.f / (float)TWO_D;

    // ---- epilogue row 0 ----
    {
        const float mean = su0 * inv_n;
        const float var  = fmaxf(sq0 * inv_n - mean * mean, 0.f);
        const float rstd = rsqrtf(var + LN_EPS);
        const float l0 = rstd * (a00 - mean * cst.x) + cst.z;
        const float l1 = rstd * (a01 - mean * cst.y) + cst.w;
        const float mx = fmaxf(l0, l1);
        const float e0 = __expf(l0 - mx), e1 = __expf(l1 - mx);
        const float inv = 1.f / (e0 + e1);
        const float w0s = e0 * inv, w1s = e1 * inv;
        f4* o4 = (f4*)(out + (size_t)r0 * D);
        #pragma unroll
        for (int j = 0; j < 3; ++j) {
            f4 o = w0s * s0[j] + w1s * m0[j];
            __builtin_nontemporal_store(o, &o4[j * 64 + lane]);
        }
    }
    // ---- epilogue row 1 ----
    if (has1) {
        const float mean = su1 * inv_n;
        const float var  = fmaxf(sq1 * inv_n - mean * mean, 0.f);
        const float rstd = rsqrtf(var + LN_EPS);
        const float l0 = rstd * (a10 - mean * cst.x) + cst.z;
        const float l1 = rstd * (a11 - mean * cst.y) + cst.w;
        const float mx = fmaxf(l0, l1);
        const float e0 = __expf(l0 - mx), e1 = __expf(l1 - mx);
        const float inv = 1.f / (e0 + e1);
        const float w0s = e0 * inv, w1s = e1 * inv;
        f4* o4 = (f4*)(out + (size_t)r1 * D);
        #pragma unroll
        for (int j = 0; j < 3; ++j) {
            f4 o = w0s * s1[j] + w1s * m1[j];
            __builtin_nontemporal_store(o, &o4[j * 64 + lane]);
        }
    }
}

extern "C" void kernel_launch(void* const* d_in, const int* in_sizes, int n_in,
                              void* d_out, int out_size, void* d_ws, size_t ws_size,
                              hipStream_t stream) {
    const float* seq    = (const float*)d_in[0];
    const float* msa    = (const float*)d_in[1];
    const float* gamma  = (const float*)d_in[2];
    const float* beta   = (const float*)d_in[3];
    const float* gate_w = (const float*)d_in[4];
    const float* gate_b = (const float*)d_in[5];
    float* out = (float*)d_out;
    float* ws  = (float*)d_ws;

    const int nrows = in_sizes[0] / D;              // 16384
    setup_kernel<<<1, 64, 0, stream>>>(gamma, beta, gate_w, gate_b, ws);
    const int blocks = (nrows + 7) / 8;             // 8 rows per block (2/wave)
    fused_gate_kernel<<<blocks, 256, 0, stream>>>(seq, msa, ws, out, nrows);
}